// Round 1
// 554.634 us; speedup vs baseline: 1.1089x; 1.1089x over previous
//
#include <hip/hip_runtime.h>
#include <stdint.h>

// Problem dims (fixed)
#define B_  4
#define L_  4096
#define D_  1024
#define H_  16
#define DH  64
#define M_  (B_*L_)   // 16384 rows

typedef _Float16 f16;
typedef __attribute__((ext_vector_type(8))) _Float16 f16x8;
typedef __attribute__((ext_vector_type(4))) _Float16 f16x4;
typedef __attribute__((ext_vector_type(4))) float    f32x4;

// ---------------- async global->LDS (16B per lane) ----------------
__device__ __forceinline__ void cp16(const void* g, void* l) {
  __builtin_amdgcn_global_load_lds(
      (const __attribute__((address_space(1))) void*)g,
      (__attribute__((address_space(3))) void*)l,
      16, 0, 0);
}

#define MFMA(a,b,c) __builtin_amdgcn_mfma_f32_16x16x32_f16(a,b,c,0,0,0)

// 8-phase sync primitives (T3+T4+T5). asm "memory" clobbers double as
// compiler fences so LDS reads/stages cannot migrate across phases.
#define PH_IN do { __builtin_amdgcn_s_barrier(); \
  asm volatile("s_waitcnt lgkmcnt(0)" ::: "memory"); \
  __builtin_amdgcn_sched_barrier(0); \
  __builtin_amdgcn_s_setprio(1); } while (0)
#define PH_OUT do { __builtin_amdgcn_s_setprio(0); \
  __builtin_amdgcn_sched_barrier(0); \
  asm volatile("" ::: "memory"); \
  __builtin_amdgcn_s_barrier(); } while (0)
#define PH_OUT_VM(nimm) do { __builtin_amdgcn_s_setprio(0); \
  __builtin_amdgcn_sched_barrier(0); \
  asm volatile("s_waitcnt vmcnt(" #nimm ")" ::: "memory"); \
  __builtin_amdgcn_s_barrier(); } while (0)

// ---------------- fp32 -> fp16 cast (8 elems/thread) ----------------
__global__ __launch_bounds__(256) void k_cvt_f16(const float* __restrict__ x,
                                                 f16* __restrict__ y, int n8) {
  int i = blockIdx.x * 256 + threadIdx.x;
  if (i >= n8) return;
  const float4* xv = (const float4*)x;
  float4 a = xv[2*i], b = xv[2*i+1];
  f16x8 o;
  o[0]=(f16)a.x; o[1]=(f16)a.y; o[2]=(f16)a.z; o[3]=(f16)a.w;
  o[4]=(f16)b.x; o[5]=(f16)b.y; o[6]=(f16)b.z; o[7]=(f16)b.w;
  ((f16x8*)y)[i] = o;
}

// ---------------- fp32 weight -> interleaved [hi;lo] catalog -------------
// W row n (output feature), hi -> cat row 32*(n>>4)+(n&15), lo -> +16.
// So in a GEMM over N'=2048, fragment pairs (j even, j odd) are hi/lo of the
// SAME 16 output columns -> fold in-register in the epilogue.
__global__ __launch_bounds__(256) void k_split_w(const float* __restrict__ x,
                                                 f16* __restrict__ cat, int n4) {
  int i = blockIdx.x * 256 + threadIdx.x;
  if (i >= n4) return;
  float4 a = ((const float4*)x)[i];
  int n  = i >> 8;        // row (0..1023): 256 float4 per 1024-col row
  int k4 = i & 255;       // float4 index within row
  f16 h0=(f16)a.x, h1=(f16)a.y, h2=(f16)a.z, h3=(f16)a.w;
  f16x4 hv = {h0, h1, h2, h3};
  f16x4 lv = {(f16)(a.x-(float)h0), (f16)(a.y-(float)h1),
              (f16)(a.z-(float)h2), (f16)(a.w-(float)h3)};
  size_t rh = (size_t)((n >> 4) * 32 + (n & 15));
  ((f16x4*)cat)[rh * 256 + k4]        = hv;
  ((f16x4*)cat)[(rh + 16) * 256 + k4] = lv;
}

// ---------------- 256x256 8-phase GEMM (T1+T2+T3+T4+T5) --------------------
// C = A * Bw^T (+bias). 512 thr = 8 waves (2M x 4N); wave tile 128x64.
// BK=64, double-buffered 128KB LDS, st-swizzle blk^=(row&7) on 16B chunks.
// mode 1: bias+sigmoid+l2norm(per 64-col head)+opt mask -> f16 (N=1024)
// mode 2: fold hi/lo pairs + bias -> f16   (N=2048 interleaved -> 1024 out)
// mode 3: fold hi/lo pairs + bias -> fp32  (N=2048 interleaved -> 1024 out)
__global__ __launch_bounds__(512, 2) void k_gemm8(
    const f16* __restrict__ A, const f16* __restrict__ Bw,
    const float* __restrict__ bias, const float* __restrict__ mask,
    float* __restrict__ Cf, f16* __restrict__ Ch, int mode,
    int M, int N, int K) {
  __shared__ __align__(16) char sA[65536];   // 2 bufs x 2 halves x 128x64 f16
  __shared__ __align__(16) char sB[65536];
  const int t = threadIdx.x;
  const int nbn = N >> 8;
  // XCD-aware swizzle (grid is 256 or 512, both % 8 == 0 -> bijective)
  int bid = blockIdx.x;
  {
    int cpx = (int)gridDim.x >> 3;
    bid = (bid & 7) * cpx + (bid >> 3);
  }
  const int bm = (bid / nbn) << 8;
  const int bn = (bid % nbn) << 8;
  const int lane = t & 63, wave = t >> 6;
  const int wm = wave >> 2;        // 0..1 : rows [wm*128, +128)
  const int wn = wave & 3;         // 0..3 : cols [wn*64, +64)
  const int fm = lane & 15, fkb = lane >> 4;   // fragment row / 16B chunk sel

  // stage one 128x64 half-tile (2 x global_load_lds per thread), source
  // pre-swizzled so linear LDS dest holds chunk (row, cb) = G(row, cb^(row&7))
  auto SA_ = [&](int T, int buf, int half) {
#pragma unroll
    for (int q = 0; q < 2; ++q) {
      int li = (q << 9) + t;
      int row = li >> 3, cb = li & 7;
      const f16* g = A + (size_t)(bm + (half << 7) + row) * K
                       + (T << 6) + ((cb ^ (row & 7)) << 3);
      cp16(g, sA + buf * 32768 + half * 16384 + li * 16);
    }
  };
  auto SB_ = [&](int T, int buf, int half) {
#pragma unroll
    for (int q = 0; q < 2; ++q) {
      int li = (q << 9) + t;
      int row = li >> 3, cb = li & 7;
      const f16* g = Bw + (size_t)(bn + (half << 7) + row) * K
                        + (T << 6) + ((cb ^ (row & 7)) << 3);
      cp16(g, sB + buf * 32768 + half * 16384 + li * 16);
    }
  };
  // swizzled fragment reads (ds_read_b128, conflict-free: 8 chunk groups)
  auto LDA = [&](int buf, int i, int ks) -> f16x8 {
    int row = (i << 4) + fm;
    int blk = ((ks << 2) + fkb) ^ (row & 7);
    return *(const f16x8*)(sA + buf * 32768 + (wm << 14) + (row << 7) + (blk << 4));
  };
  auto LDB = [&](int buf, int j, int ks) -> f16x8 {
    int row = ((wn & 1) << 6) + (j << 4) + fm;
    int blk = ((ks << 2) + fkb) ^ (row & 7);
    return *(const f16x8*)(sB + buf * 32768 + ((wn >> 1) << 14) + (row << 7) + (blk << 4));
  };

  f32x4 acc[8][4] = {};

  // ---- prologue: tile0 full into buf0, tile1 B into buf1 (A1 comes at p1/p2)
  SA_(0, 0, 0); SA_(0, 0, 1);
  SB_(0, 0, 0); SB_(0, 0, 1);
  SB_(1, 1, 0); SB_(1, 1, 1);
  asm volatile("s_waitcnt vmcnt(4)" ::: "memory");   // buf0 landed; b1.B in flight
  __builtin_amdgcn_s_barrier();

  const int NI = K >> 7;          // iterations, 2 K-tiles each (K=1024 -> 8)
  for (int it = 0; it < NI; ++it) {
    const bool nl = (it != NI - 1);
    const int t2 = 2 * it + 2, t3 = 2 * it + 3;
    f16x8 aL[4][2], aH[4][2], bA[2][2], bB[2][2];

    // ---- phase 1 (buf0): read aL,bA; stage b1.A h0 (tile 2it+1)
#pragma unroll
    for (int i = 0; i < 4; ++i) { aL[i][0] = LDA(0,i,0); aL[i][1] = LDA(0,i,1); }
#pragma unroll
    for (int j = 0; j < 2; ++j) { bA[j][0] = LDB(0,j,0); bA[j][1] = LDB(0,j,1); }
    SA_(2*it+1, 1, 0);
    PH_IN;
#pragma unroll
    for (int i = 0; i < 4; ++i)
#pragma unroll
      for (int j = 0; j < 2; ++j) {
        acc[i][j] = MFMA(aL[i][0], bA[j][0], acc[i][j]);
        acc[i][j] = MFMA(aL[i][1], bA[j][1], acc[i][j]);
      }
    PH_OUT;
    // ---- phase 2: read bB; stage b1.A h1
#pragma unroll
    for (int j = 0; j < 2; ++j) { bB[j][0] = LDB(0,j+2,0); bB[j][1] = LDB(0,j+2,1); }
    SA_(2*it+1, 1, 1);
    PH_IN;
#pragma unroll
    for (int i = 0; i < 4; ++i)
#pragma unroll
      for (int j = 0; j < 2; ++j) {
        acc[i][j+2] = MFMA(aL[i][0], bB[j][0], acc[i][j+2]);
        acc[i][j+2] = MFMA(aL[i][1], bB[j][1], acc[i][j+2]);
      }
    PH_OUT;
    // ---- phase 3: read aH; stage b0.B h0 (tile t2)  [sB buf0 free after p2]
#pragma unroll
    for (int i = 0; i < 4; ++i) { aH[i][0] = LDA(0,i+4,0); aH[i][1] = LDA(0,i+4,1); }
    if (nl) SB_(t2, 0, 0);
    PH_IN;
#pragma unroll
    for (int i = 0; i < 4; ++i)
#pragma unroll
      for (int j = 0; j < 2; ++j) {
        acc[i+4][j] = MFMA(aH[i][0], bA[j][0], acc[i+4][j]);
        acc[i+4][j] = MFMA(aH[i][1], bA[j][1], acc[i+4][j]);
      }
    PH_OUT;
    // ---- phase 4: no reads; stage b0.B h1; vmcnt -> b1 fully landed
    if (nl) SB_(t2, 0, 1);
    PH_IN;
#pragma unroll
    for (int i = 0; i < 4; ++i)
#pragma unroll
      for (int j = 0; j < 2; ++j) {
        acc[i+4][j+2] = MFMA(aH[i][0], bB[j][0], acc[i+4][j+2]);
        acc[i+4][j+2] = MFMA(aH[i][1], bB[j][1], acc[i+4][j+2]);
      }
    if (nl) PH_OUT_VM(4); else PH_OUT_VM(0);
    // ---- phase 5 (buf1): read aL,bA; stage b0.A h0 (t2) [sA buf0 free after p3]
#pragma unroll
    for (int i = 0; i < 4; ++i) { aL[i][0] = LDA(1,i,0); aL[i][1] = LDA(1,i,1); }
#pragma unroll
    for (int j = 0; j < 2; ++j) { bA[j][0] = LDB(1,j,0); bA[j][1] = LDB(1,j,1); }
    if (nl) SA_(t2, 0, 0);
    PH_IN;
#pragma unroll
    for (int i = 0; i < 4; ++i)
#pragma unroll
      for (int j = 0; j < 2; ++j) {
        acc[i][j] = MFMA(aL[i][0], bA[j][0], acc[i][j]);
        acc[i][j] = MFMA(aL[i][1], bA[j][1], acc[i][j]);
      }
    PH_OUT;
    // ---- phase 6: read bB; stage b0.A h1
#pragma unroll
    for (int j = 0; j < 2; ++j) { bB[j][0] = LDB(1,j+2,0); bB[j][1] = LDB(1,j+2,1); }
    if (nl) SA_(t2, 0, 1);
    PH_IN;
#pragma unroll
    for (int i = 0; i < 4; ++i)
#pragma unroll
      for (int j = 0; j < 2; ++j) {
        acc[i][j+2] = MFMA(aL[i][0], bB[j][0], acc[i][j+2]);
        acc[i][j+2] = MFMA(aL[i][1], bB[j][1], acc[i][j+2]);
      }
    PH_OUT;
    // ---- phase 7: read aH; stage b1.B h0 (t3) [sB buf1 free after p6]
#pragma unroll
    for (int i = 0; i < 4; ++i) { aH[i][0] = LDA(1,i+4,0); aH[i][1] = LDA(1,i+4,1); }
    if (nl) SB_(t3, 1, 0);
    PH_IN;
#pragma unroll
    for (int i = 0; i < 4; ++i)
#pragma unroll
      for (int j = 0; j < 2; ++j) {
        acc[i+4][j] = MFMA(aH[i][0], bA[j][0], acc[i+4][j]);
        acc[i+4][j] = MFMA(aH[i][1], bA[j][1], acc[i+4][j]);
      }
    PH_OUT;
    // ---- phase 8: stage b1.B h1; vmcnt -> b0 (tile t2) fully landed
    if (nl) SB_(t3, 1, 1);
    PH_IN;
#pragma unroll
    for (int i = 0; i < 4; ++i)
#pragma unroll
      for (int j = 0; j < 2; ++j) {
        acc[i+4][j+2] = MFMA(aH[i][0], bB[j][0], acc[i+4][j+2]);
        acc[i+4][j+2] = MFMA(aH[i][1], bB[j][1], acc[i+4][j+2]);
      }
    PH_OUT_VM(4);
  }

  // ---------------- epilogue ----------------
  // C/D layout: col = lane&15, row = (lane>>4)*4 + reg  [m89/m91]
  const int cr = (lane >> 4) << 2, ccol = lane & 15;
  const int rowbase = bm + wm * 128;
  if (mode == 1) {
    const int No = N;
    float bvj[4];
#pragma unroll
    for (int j = 0; j < 4; ++j) bvj[j] = bias[bn + wn*64 + j*16 + ccol];
#pragma unroll
    for (int i = 0; i < 8; ++i)
#pragma unroll
      for (int r = 0; r < 4; ++r) {
        int gm = rowbase + i*16 + cr + r;
        float s[4], ss = 0.f;
#pragma unroll
        for (int j = 0; j < 4; ++j) {
          float v = acc[i][j][r] + bvj[j];
          s[j] = 1.0f / (1.0f + __expf(-v));
          ss += s[j] * s[j];
        }
        ss += __shfl_xor(ss, 1, 64);
        ss += __shfl_xor(ss, 2, 64);
        ss += __shfl_xor(ss, 4, 64);
        ss += __shfl_xor(ss, 8, 64);
        float sc = 1.0f / fmaxf(sqrtf(ss), 1e-12f);
        if (mask) sc *= mask[gm];
#pragma unroll
        for (int j = 0; j < 4; ++j)
          Ch[(size_t)gm * No + bn + wn*64 + j*16 + ccol] = (f16)(s[j] * sc);
      }
  } else {
    const int No = N >> 1;    // folded output width (1024)
#pragma unroll
    for (int j2 = 0; j2 < 2; ++j2) {
      int colp = bn + wn*64 + (2*j2)*16;        // interleaved 2048-space
      int oc = ((colp >> 5) << 4) + ccol;       // output column
      float bv = bias[oc];
#pragma unroll
      for (int i = 0; i < 8; ++i)
#pragma unroll
        for (int r = 0; r < 4; ++r) {
          int gm = rowbase + i*16 + cr + r;
          float v = acc[i][2*j2][r] + acc[i][2*j2+1][r] + bv;
          if (mode == 2) Ch[(size_t)gm * No + oc] = (f16)v;
          else           Cf[(size_t)gm * No + oc] = v;
        }
    }
  }
}

// ---------------- kv via MFMA: per (head, chunk of 512 rows) ---------------
#define SKT 72
__global__ __launch_bounds__(256) void k_kv_mfma(const f16* __restrict__ Kh,
                                                 const f16* __restrict__ Vh,
                                                 float* __restrict__ part) {
  __shared__ __align__(16) f16 sKt[64 * SKT];    // [d][l]
  __shared__ __align__(16) f16 sVt[128 * SKT];   // [c2][l]
  int head = blockIdx.x >> 3, chunk = blockIdx.x & 7;
  int b = head >> 4, h = head & 15;
  int t = threadIdx.x, lane = t & 63, wave = t >> 6;
  int lp = t & 31, g8 = (t >> 5) << 3;
  size_t rowbase = (size_t)b * L_ + (size_t)chunk * 512;
  const f16* Kb = Kh + rowbase * D_ + h * DH;
  const f16* Vb = Vh + rowbase * D_ + h * DH;

  const int fm = lane & 15, fk = (lane >> 4) << 3;
  const int wm2 = (wave & 1) * 2;
  const int wn4 = (wave >> 1) * 4;
  f32x4 acc[2][4] = {};

  for (int l0 = 0; l0 < 512; l0 += 64) {
    __syncthreads();
    {
      const f16* r0 = Kb + (size_t)(l0 + 2*lp) * D_ + g8;
      f16x8 a0 = *(const f16x8*)r0;
      f16x8 a1 = *(const f16x8*)(r0 + D_);
#pragma unroll
      for (int j = 0; j < 8; ++j) {
        union { f16 h2[2]; uint32_t u; } pk;
        pk.h2[0] = a0[j]; pk.h2[1] = a1[j];
        *(uint32_t*)&sKt[(g8 + j) * SKT + 2*lp] = pk.u;
      }
      const f16* v0p = Vb + (size_t)(l0 + 2*lp) * D_ + g8;
      f16x8 b0 = *(const f16x8*)v0p;
      f16x8 b1 = *(const f16x8*)(v0p + D_);
#pragma unroll
      for (int j = 0; j < 8; ++j) {
        float x0 = (float)b0[j], x1 = (float)b1[j];
        union { f16 h2[2]; uint32_t u; } pp, pm;
        pp.h2[0] = (f16)fmaxf(x0, 0.f); pp.h2[1] = (f16)fmaxf(x1, 0.f);
        pm.h2[0] = (f16)fminf(x0, 0.f); pm.h2[1] = (f16)fminf(x1, 0.f);
        *(uint32_t*)&sVt[(g8 + j) * SKT + 2*lp]        = pp.u;
        *(uint32_t*)&sVt[(64 + g8 + j) * SKT + 2*lp]   = pm.u;
      }
    }
    __syncthreads();
#pragma unroll
    for (int ks = 0; ks < 2; ++ks) {
      f16x8 af[2], bf[4];
#pragma unroll
      for (int i = 0; i < 2; ++i)
        af[i] = *(const f16x8*)&sKt[((wm2+i)*16 + fm) * SKT + ks*32 + fk];
#pragma unroll
      for (int j = 0; j < 4; ++j)
        bf[j] = *(const f16x8*)&sVt[((wn4+j)*16 + fm) * SKT + ks*32 + fk];
#pragma unroll
      for (int i = 0; i < 2; ++i)
#pragma unroll
        for (int j = 0; j < 4; ++j)
          acc[i][j] = MFMA(af[i], bf[j], acc[i][j]);
    }
  }
  const int cr = (lane >> 4) << 2, ccol = lane & 15;
  float* pb = part + (size_t)(head * 8 + chunk) * 8192;
#pragma unroll
  for (int i = 0; i < 2; ++i)
#pragma unroll
    for (int j = 0; j < 4; ++j) {
      int d = (wm2 + i) * 16 + cr;
      int c2 = (wn4 + j) * 16 + ccol;
#pragma unroll
      for (int r = 0; r < 4; ++r)
        pb[(d + r) * 128 + c2] = acc[i][j][r];
    }
}

__global__ __launch_bounds__(256) void k_kv_reduce(const float* __restrict__ part,
                                                   float* __restrict__ kv) {
  int i = blockIdx.x * 256 + threadIdx.x;
  int head = i >> 13, dc = i & 8191;
  float s = 0.f;
#pragma unroll
  for (int c = 0; c < 8; ++c) s += part[(size_t)(head * 8 + c) * 8192 + dc];
  kv[i] = s;
}

__global__ __launch_bounds__(256) void k_kv_cvt(const float* __restrict__ kvb,
                                                f16* __restrict__ kvh) {
  int head = blockIdx.x, t = threadIdx.x;
  int c = t >> 1, half = t & 1;
  const float* src = kvb + (size_t)head * 8192 + half * 32 * 128 + c;
  f16* dst = kvh + (size_t)head * 8192 + c * 64 + half * 32;
  f16 buf[32];
#pragma unroll
  for (int kk = 0; kk < 32; ++kk) buf[kk] = (f16)src[kk * 128];
#pragma unroll
  for (int q = 0; q < 4; ++q) ((f16x8*)dst)[q] = *(const f16x8*)&buf[q * 8];
}

// ---------------- heads via MFMA: o = l2n(Q@kv+) + l2n(Q@kv-) --------------
#define SH 72
__global__ __launch_bounds__(256) void k_heads_mfma(const f16* __restrict__ Qh,
                                                    const f16* __restrict__ kvh,
                                                    f16* __restrict__ O) {
  __shared__ __align__(16) f16 sQ [128 * SH];
  __shared__ __align__(16) f16 sKV[128 * SH];
  int bi = blockIdx.x;
  int head = bi >> 5, mt = bi & 31;
  int b = head >> 4, h = head & 15;
  int t = threadIdx.x, lane = t & 63, wave = t >> 6;
  size_t qbase = ((size_t)(b * L_ + mt * 128)) * D_ + h * DH;
  const f16* kvp = kvh + (size_t)head * 8192;
#pragma unroll
  for (int p = 0; p < 4; ++p) {
    int c = p * 256 + t;
    int row = c >> 3, off = (c & 7) * 8;
    f16x8 q = *(const f16x8*)(Qh + qbase + (size_t)row * D_ + off);
    *(f16x8*)&sQ[row * SH + off] = q;
    f16x8 kv8 = *(const f16x8*)(kvp + row * 64 + off);
    *(f16x8*)&sKV[row * SH + off] = kv8;
  }
  __syncthreads();

  const int fm = lane & 15, fk = (lane >> 4) << 3;
  const int wm = wave * 32;
  f32x4 acc[2][8] = {};
#pragma unroll
  for (int ks = 0; ks < 2; ++ks) {
    f16x8 a0 = *(const f16x8*)&sQ[(wm + fm) * SH + ks * 32 + fk];
    f16x8 a1 = *(const f16x8*)&sQ[(wm + 16 + fm) * SH + ks * 32 + fk];
#pragma unroll
    for (int j = 0; j < 8; ++j) {
      f16x8 bj = *(const f16x8*)&sKV[(j * 16 + fm) * SH + ks * 32 + fk];
      acc[0][j] = MFMA(a0, bj, acc[0][j]);
      acc[1][j] = MFMA(a1, bj, acc[1][j]);
    }
  }
  const int cr = (lane >> 4) << 2, ccol = lane & 15;
#pragma unroll
  for (int i = 0; i < 2; ++i)
#pragma unroll
    for (int r = 0; r < 4; ++r) {
      int row = wm + i * 16 + cr + r;
      float sp = 0.f, sm = 0.f;
#pragma unroll
      for (int j = 0; j < 4; ++j) {
        sp += acc[i][j][r] * acc[i][j][r];
        sm += acc[i][j + 4][r] * acc[i][j + 4][r];
      }
      sp += __shfl_xor(sp, 1, 64); sm += __shfl_xor(sm, 1, 64);
      sp += __shfl_xor(sp, 2, 64); sm += __shfl_xor(sm, 2, 64);
      sp += __shfl_xor(sp, 4, 64); sm += __shfl_xor(sm, 4, 64);
      sp += __shfl_xor(sp, 8, 64); sm += __shfl_xor(sm, 8, 64);
      float rp = 1.0f / fmaxf(sqrtf(sp), 1e-12f);
      float rm = 1.0f / fmaxf(sqrtf(sm), 1e-12f);
#pragma unroll
      for (int j = 0; j < 4; ++j) {
        float o = acc[i][j][r] * rp + acc[i][j + 4][r] * rm;
        O[qbase + (size_t)row * D_ + j * 16 + ccol] = (f16)o;
      }
    }
}

// ---------------- launch ----------------
extern "C" void kernel_launch(void* const* d_in, const int* in_sizes, int n_in,
                              void* d_out, int out_size, void* d_ws, size_t ws_size,
                              hipStream_t stream) {
  const float* queries = (const float*)d_in[0];
  const float* values  = (const float*)d_in[1];
  const float* keys    = (const float*)d_in[2];
  const float* mask    = (const float*)d_in[3];
  const float* Wq = (const float*)d_in[4];  const float* bq = (const float*)d_in[5];
  const float* Wk = (const float*)d_in[6];  const float* bk = (const float*)d_in[7];
  const float* Wv = (const float*)d_in[8];  const float* bv = (const float*)d_in[9];
  const float* Wo = (const float*)d_in[10]; const float* bo = (const float*)d_in[11];
  float* out = (float*)d_out;

  const size_t MB = 1024ull * 1024ull;
  const size_t NEED = 160 * MB;
  if (ws_size < NEED) return;

  char* ws = (char*)d_ws;
  const size_t DD = (size_t)D_ * D_;
  f16*   Wqh  = (f16*)(ws);                 // 2MB
  f16*   Wkh  = (f16*)(ws + 2 * MB);        // 2MB
  f16*   Wcv  = (f16*)(ws + 4 * MB);        // 4MB interleaved [hi;lo] V weight
  f16*   Wco  = (f16*)(ws + 8 * MB);        // 4MB interleaved [hi;lo] O weight
  f16*   Ah   = (f16*)(ws + 12 * MB);       // 32MB (A-side f16; reused for heads)
  f16*   Qh   = (f16*)(ws + 44 * MB);       // 32MB
  float* kvb  = (float*)(ws + 76 * MB);     // 2MB
  f16*   kvh  = (f16*)(ws + 78 * MB);       // 1MB (+1MB pad)
  float* part = (float*)(ws + 80 * MB);     // 16MB
  f16*   kp   = (f16*)(ws + 96 * MB);       // 32MB
  f16*   vp   = (f16*)(ws + 128 * MB);      // 32MB -> 160MB

  const int DD8 = (int)(DD / 8);            // 131072
  const int DD4 = (int)(DD / 4);            // 262144
  k_cvt_f16<<<DD8 / 256, 256, 0, stream>>>(Wq, Wqh, DD8);
  k_cvt_f16<<<DD8 / 256, 256, 0, stream>>>(Wk, Wkh, DD8);
  k_split_w<<<DD4 / 256, 256, 0, stream>>>(Wv, Wcv, DD4);
  k_split_w<<<DD4 / 256, 256, 0, stream>>>(Wo, Wco, DD4);

  const int n8 = M_ * D_ / 8;
  const int g1 = (M_ / 256) * (1024 / 256);   // 256 blocks (N=1024)
  const int g2 = (M_ / 256) * (2048 / 256);   // 512 blocks (N'=2048)

  k_cvt_f16<<<n8 / 256, 256, 0, stream>>>(queries, Ah, n8);
  k_gemm8<<<g1, 512, 0, stream>>>(Ah, Wqh, bq, nullptr, nullptr, Qh, 1, M_, 1024, 1024);
  k_cvt_f16<<<n8 / 256, 256, 0, stream>>>(keys, Ah, n8);
  k_gemm8<<<g1, 512, 0, stream>>>(Ah, Wkh, bk, mask, nullptr, kp, 1, M_, 1024, 1024);
  k_cvt_f16<<<n8 / 256, 256, 0, stream>>>(values, Ah, n8);
  k_gemm8<<<g2, 512, 0, stream>>>(Ah, Wcv, bv, nullptr, nullptr, vp, 2, M_, 2048, 1024);

  k_kv_mfma<<<64 * 8, 256, 0, stream>>>(kp, vp, part);
  k_kv_reduce<<<64 * 8192 / 256, 256, 0, stream>>>(part, kvb);
  k_kv_cvt<<<64, 256, 0, stream>>>(kvb, kvh);
  k_heads_mfma<<<64 * 32, 256, 0, stream>>>(Qh, kvh, Ah);

  k_gemm8<<<g2, 512, 0, stream>>>(Ah, Wco, bo, nullptr, out, nullptr, 3, M_, 2048, 1024);
}

// Round 2
// 504.273 us; speedup vs baseline: 1.2196x; 1.0999x over previous
//
#include <hip/hip_runtime.h>
#include <stdint.h>

// Problem dims (fixed)
#define B_  4
#define L_  4096
#define D_  1024
#define H_  16
#define DH  64
#define M_  (B_*L_)   // 16384 rows

typedef _Float16 f16;
typedef __attribute__((ext_vector_type(8))) _Float16 f16x8;
typedef __attribute__((ext_vector_type(4))) _Float16 f16x4;
typedef __attribute__((ext_vector_type(4))) float    f32x4;

// ---------------- async global->LDS (16B per lane) ----------------
__device__ __forceinline__ void cp16(const void* g, void* l) {
  __builtin_amdgcn_global_load_lds(
      (const __attribute__((address_space(1))) void*)g,
      (__attribute__((address_space(3))) void*)l,
      16, 0, 0);
}

#define MFMA(a,b,c) __builtin_amdgcn_mfma_f32_16x16x32_f16(a,b,c,0,0,0)

// 8-phase sync primitives (T3+T4+T5).
#define PH_IN do { __builtin_amdgcn_s_barrier(); \
  asm volatile("s_waitcnt lgkmcnt(0)" ::: "memory"); \
  __builtin_amdgcn_sched_barrier(0); \
  __builtin_amdgcn_s_setprio(1); } while (0)
#define PH_OUT do { __builtin_amdgcn_s_setprio(0); \
  __builtin_amdgcn_sched_barrier(0); \
  asm volatile("" ::: "memory"); \
  __builtin_amdgcn_s_barrier(); } while (0)
#define PH_OUT_VM(nimm) do { __builtin_amdgcn_s_setprio(0); \
  __builtin_amdgcn_sched_barrier(0); \
  asm volatile("s_waitcnt vmcnt(" #nimm ")" ::: "memory"); \
  __builtin_amdgcn_s_barrier(); } while (0)

// ---------------- fp32 -> fp16 cast (8 elems/thread) ----------------
__global__ __launch_bounds__(256) void k_cvt_f16(const float* __restrict__ x,
                                                 f16* __restrict__ y, int n8) {
  int i = blockIdx.x * 256 + threadIdx.x;
  if (i >= n8) return;
  const float4* xv = (const float4*)x;
  float4 a = xv[2*i], b = xv[2*i+1];
  f16x8 o;
  o[0]=(f16)a.x; o[1]=(f16)a.y; o[2]=(f16)a.z; o[3]=(f16)a.w;
  o[4]=(f16)b.x; o[5]=(f16)b.y; o[6]=(f16)b.z; o[7]=(f16)b.w;
  ((f16x8*)y)[i] = o;
}

// two-source variant (n8each must be multiple of 256)
__global__ __launch_bounds__(256) void k_cvt2(const float* __restrict__ x0,
                                              f16* __restrict__ y0,
                                              const float* __restrict__ x1,
                                              f16* __restrict__ y1, int n8each) {
  int i = blockIdx.x * 256 + threadIdx.x;
  const float* x = x0; f16* y = y0;
  if (i >= n8each) { x = x1; y = y1; i -= n8each; }
  const float4* xv = (const float4*)x;
  float4 a = xv[2*i], b = xv[2*i+1];
  f16x8 o;
  o[0]=(f16)a.x; o[1]=(f16)a.y; o[2]=(f16)a.z; o[3]=(f16)a.w;
  o[4]=(f16)b.x; o[5]=(f16)b.y; o[6]=(f16)b.z; o[7]=(f16)b.w;
  ((f16x8*)y)[i] = o;
}

// ---------------- fp32 weight -> interleaved [hi;lo] catalog -------------
// W row n: hi -> cat row 32*(n>>4)+(n&15), lo -> +16.
__device__ __forceinline__ void split_one(const float* __restrict__ x,
                                          f16* __restrict__ cat, int i) {
  float4 a = ((const float4*)x)[i];
  int n  = i >> 8;
  int k4 = i & 255;
  f16 h0=(f16)a.x, h1=(f16)a.y, h2=(f16)a.z, h3=(f16)a.w;
  f16x4 hv = {h0, h1, h2, h3};
  f16x4 lv = {(f16)(a.x-(float)h0), (f16)(a.y-(float)h1),
              (f16)(a.z-(float)h2), (f16)(a.w-(float)h3)};
  size_t rh = (size_t)((n >> 4) * 32 + (n & 15));
  ((f16x4*)cat)[rh * 256 + k4]        = hv;
  ((f16x4*)cat)[(rh + 16) * 256 + k4] = lv;
}

__global__ __launch_bounds__(256) void k_split2(const float* __restrict__ x0,
                                                f16* __restrict__ c0,
                                                const float* __restrict__ x1,
                                                f16* __restrict__ c1, int n4each) {
  int i = blockIdx.x * 256 + threadIdx.x;
  if (i < n4each) split_one(x0, c0, i);
  else            split_one(x1, c1, i - n4each);
}

// ---------------- 256x256 8-phase GEMM (T1+T2+T3+T4+T5) --------------------
// 512 thr = 8 waves (2M x 4N); wave tile 128x64; BK=64, dbuf 128KB LDS,
// swizzle blk^=(row&7) on 16B chunks. Epilogue stages into LDS and emits
// coalesced wide stores (fix: 1.5-3x write amplification from scattered
// fragment stores seen in rocprof WRITE_SIZE).
// mode 1: bias+sigmoid+l2norm(64-col head)+opt mask -> f16 (N=1024)
// mode 2: fold hi/lo pairs + bias -> f16   (N=2048 interleaved -> 1024)
// mode 3: fold hi/lo pairs + bias -> fp32  (N=2048 interleaved -> 1024)
struct GemmJob {
  const f16* A; const f16* Bw; const float* bias; const float* mask;
  float* Cf; f16* Ch; int mode; int N;
};

__global__ __launch_bounds__(512, 2) void k_gemm8(GemmJob j0, GemmJob j1,
                                                  int nblk0, int M, int K) {
  // 131072 for K-loop dbuf; 137216 for mode-1 epilogue staging [128][268] f32
  __shared__ __align__(16) char smem[137216];
  char* sA = smem;
  char* sB = smem + 65536;
  const int t = threadIdx.x;

  int raw = (int)blockIdx.x;
  GemmJob J; int bid, nblk;
  if (raw < nblk0) { J = j0; bid = raw;         nblk = nblk0; }
  else             { J = j1; bid = raw - nblk0; nblk = (int)gridDim.x - nblk0; }
  const int N = J.N;
  const int nbn = N >> 8;
  { // XCD-aware swizzle within job (job sizes are multiples of 8)
    int cpx = nblk >> 3;
    bid = (bid & 7) * cpx + (bid >> 3);
  }
  const int bm = (bid / nbn) << 8;
  const int bn = (bid % nbn) << 8;
  const int lane = t & 63, wave = t >> 6;
  const int wm = wave >> 2;        // 0..1 : rows [wm*128, +128)
  const int wn = wave & 3;         // 0..3 : cols [wn*64, +64)
  const int fm = lane & 15, fkb = lane >> 4;

  const f16* Ab = J.A;
  const f16* Bb = J.Bw;
  auto SA_ = [&](int T, int buf, int half) {
#pragma unroll
    for (int q = 0; q < 2; ++q) {
      int li = (q << 9) + t;
      int row = li >> 3, cb = li & 7;
      const f16* g = Ab + (size_t)(bm + (half << 7) + row) * K
                        + (T << 6) + ((cb ^ (row & 7)) << 3);
      cp16(g, sA + buf * 32768 + half * 16384 + li * 16);
    }
  };
  auto SB_ = [&](int T, int buf, int half) {
#pragma unroll
    for (int q = 0; q < 2; ++q) {
      int li = (q << 9) + t;
      int row = li >> 3, cb = li & 7;
      const f16* g = Bb + (size_t)(bn + (half << 7) + row) * K
                        + (T << 6) + ((cb ^ (row & 7)) << 3);
      cp16(g, sB + buf * 32768 + half * 16384 + li * 16);
    }
  };
  auto LDA = [&](int buf, int i, int ks) -> f16x8 {
    int row = (i << 4) + fm;
    int blk = ((ks << 2) + fkb) ^ (row & 7);
    return *(const f16x8*)(sA + buf * 32768 + (wm << 14) + (row << 7) + (blk << 4));
  };
  auto LDB = [&](int buf, int j, int ks) -> f16x8 {
    int row = ((wn & 1) << 6) + (j << 4) + fm;
    int blk = ((ks << 2) + fkb) ^ (row & 7);
    return *(const f16x8*)(sB + buf * 32768 + ((wn >> 1) << 14) + (row << 7) + (blk << 4));
  };

  f32x4 acc[8][4] = {};

  // ---- prologue
  SA_(0, 0, 0); SA_(0, 0, 1);
  SB_(0, 0, 0); SB_(0, 0, 1);
  SB_(1, 1, 0); SB_(1, 1, 1);
  asm volatile("s_waitcnt vmcnt(4)" ::: "memory");
  __builtin_amdgcn_s_barrier();

  const int NI = K >> 7;
  for (int it = 0; it < NI; ++it) {
    const bool nl = (it != NI - 1);
    const int t2 = 2 * it + 2, t3 = 2 * it + 3;
    f16x8 aL[4][2], aH[4][2], bA[2][2], bB[2][2];

    // p1 (buf0): read aL,bA; stage b1.A h0
#pragma unroll
    for (int i = 0; i < 4; ++i) { aL[i][0] = LDA(0,i,0); aL[i][1] = LDA(0,i,1); }
#pragma unroll
    for (int j = 0; j < 2; ++j) { bA[j][0] = LDB(0,j,0); bA[j][1] = LDB(0,j,1); }
    SA_(2*it+1, 1, 0);
    PH_IN;
#pragma unroll
    for (int i = 0; i < 4; ++i)
#pragma unroll
      for (int j = 0; j < 2; ++j) {
        acc[i][j] = MFMA(aL[i][0], bA[j][0], acc[i][j]);
        acc[i][j] = MFMA(aL[i][1], bA[j][1], acc[i][j]);
      }
    PH_OUT;
    // p2: read bB; stage b1.A h1
#pragma unroll
    for (int j = 0; j < 2; ++j) { bB[j][0] = LDB(0,j+2,0); bB[j][1] = LDB(0,j+2,1); }
    SA_(2*it+1, 1, 1);
    PH_IN;
#pragma unroll
    for (int i = 0; i < 4; ++i)
#pragma unroll
      for (int j = 0; j < 2; ++j) {
        acc[i][j+2] = MFMA(aL[i][0], bB[j][0], acc[i][j+2]);
        acc[i][j+2] = MFMA(aL[i][1], bB[j][1], acc[i][j+2]);
      }
    PH_OUT;
    // p3: read aH; stage b0.B h0
#pragma unroll
    for (int i = 0; i < 4; ++i) { aH[i][0] = LDA(0,i+4,0); aH[i][1] = LDA(0,i+4,1); }
    if (nl) SB_(t2, 0, 0);
    PH_IN;
#pragma unroll
    for (int i = 0; i < 4; ++i)
#pragma unroll
      for (int j = 0; j < 2; ++j) {
        acc[i+4][j] = MFMA(aH[i][0], bA[j][0], acc[i+4][j]);
        acc[i+4][j] = MFMA(aH[i][1], bA[j][1], acc[i+4][j]);
      }
    PH_OUT;
    // p4: stage b0.B h1; vmcnt -> b1 landed
    if (nl) SB_(t2, 0, 1);
    PH_IN;
#pragma unroll
    for (int i = 0; i < 4; ++i)
#pragma unroll
      for (int j = 0; j < 2; ++j) {
        acc[i+4][j+2] = MFMA(aH[i][0], bB[j][0], acc[i+4][j+2]);
        acc[i+4][j+2] = MFMA(aH[i][1], bB[j][1], acc[i+4][j+2]);
      }
    if (nl) PH_OUT_VM(4); else PH_OUT_VM(0);
    // p5 (buf1)
#pragma unroll
    for (int i = 0; i < 4; ++i) { aL[i][0] = LDA(1,i,0); aL[i][1] = LDA(1,i,1); }
#pragma unroll
    for (int j = 0; j < 2; ++j) { bA[j][0] = LDB(1,j,0); bA[j][1] = LDB(1,j,1); }
    if (nl) SA_(t2, 0, 0);
    PH_IN;
#pragma unroll
    for (int i = 0; i < 4; ++i)
#pragma unroll
      for (int j = 0; j < 2; ++j) {
        acc[i][j] = MFMA(aL[i][0], bA[j][0], acc[i][j]);
        acc[i][j] = MFMA(aL[i][1], bA[j][1], acc[i][j]);
      }
    PH_OUT;
    // p6
#pragma unroll
    for (int j = 0; j < 2; ++j) { bB[j][0] = LDB(1,j+2,0); bB[j][1] = LDB(1,j+2,1); }
    if (nl) SA_(t2, 0, 1);
    PH_IN;
#pragma unroll
    for (int i = 0; i < 4; ++i)
#pragma unroll
      for (int j = 0; j < 2; ++j) {
        acc[i][j+2] = MFMA(aL[i][0], bB[j][0], acc[i][j+2]);
        acc[i][j+2] = MFMA(aL[i][1], bB[j][1], acc[i][j+2]);
      }
    PH_OUT;
    // p7
#pragma unroll
    for (int i = 0; i < 4; ++i) { aH[i][0] = LDA(1,i+4,0); aH[i][1] = LDA(1,i+4,1); }
    if (nl) SB_(t3, 1, 0);
    PH_IN;
#pragma unroll
    for (int i = 0; i < 4; ++i)
#pragma unroll
      for (int j = 0; j < 2; ++j) {
        acc[i+4][j] = MFMA(aH[i][0], bA[j][0], acc[i+4][j]);
        acc[i+4][j] = MFMA(aH[i][1], bA[j][1], acc[i+4][j]);
      }
    PH_OUT;
    // p8: stage b1.B h1; vmcnt -> b0 landed
    if (nl) SB_(t3, 1, 1);
    PH_IN;
#pragma unroll
    for (int i = 0; i < 4; ++i)
#pragma unroll
      for (int j = 0; j < 2; ++j) {
        acc[i+4][j+2] = MFMA(aH[i][0], bB[j][0], acc[i+4][j+2]);
        acc[i+4][j+2] = MFMA(aH[i][1], bB[j][1], acc[i+4][j+2]);
      }
    PH_OUT_VM(4);
  }

  // ---------------- epilogue (LDS-coalesced stores) ----------------
  // C/D layout: col = lane&15, row = (lane>>4)*4 + reg  [m89/m91]
  const int cr = (lane >> 4) << 2, ccol = lane & 15;
  const int rowbase = bm + wm * 128;
  float* sOut = (float*)smem;
  if (J.mode == 1) {
    // stage fp32 s[j]*sc into sOut[128][268] (row pitch 268: +4 rows -> +16 banks)
    float bvj[4];
#pragma unroll
    for (int j = 0; j < 4; ++j) bvj[j] = J.bias[bn + wn*64 + j*16 + ccol];
    for (int h = 0; h < 2; ++h) {
      if (wm == h) {
#pragma unroll
        for (int i = 0; i < 8; ++i)
#pragma unroll
          for (int r = 0; r < 4; ++r) {
            int rl = i*16 + cr + r;         // 0..127 within this half
            int gm = rowbase + rl;
            float s[4], ss = 0.f;
#pragma unroll
            for (int j = 0; j < 4; ++j) {
              float v = acc[i][j][r] + bvj[j];
              s[j] = 1.0f / (1.0f + __expf(-v));
              ss += s[j] * s[j];
            }
            ss += __shfl_xor(ss, 1, 64);
            ss += __shfl_xor(ss, 2, 64);
            ss += __shfl_xor(ss, 4, 64);
            ss += __shfl_xor(ss, 8, 64);
            float sc = 1.0f / fmaxf(sqrtf(ss), 1e-12f);
            if (J.mask) sc *= J.mask[gm];
#pragma unroll
            for (int j = 0; j < 4; ++j)
              sOut[rl*268 + wn*64 + j*16 + ccol] = s[j] * sc;
          }
      }
      __syncthreads();
      // readback: 512B contiguous f16 segments per row
#pragma unroll
      for (int sp = 0; sp < 16; ++sp) {
        int rl = sp*8 + (t >> 6);
        int c4 = (t & 63) * 4;
        f32x4 v = *(const f32x4*)&sOut[rl*268 + c4];
        f16x4 o = {(f16)v[0], (f16)v[1], (f16)v[2], (f16)v[3]};
        *(f16x4*)&J.Ch[(size_t)(bm + h*128 + rl) * N + bn + c4] = o;
      }
      __syncthreads();
    }
  } else {
    // fold hi/lo, stage into sOut[256][132] (pitch 132: +4 rows -> +16 banks)
#pragma unroll
    for (int j2 = 0; j2 < 2; ++j2) {
      int ocl = wn*32 + j2*16 + ccol;       // 0..127 block-local real col
      float bv = J.bias[(bn >> 1) + ocl];
#pragma unroll
      for (int i = 0; i < 8; ++i)
#pragma unroll
        for (int r = 0; r < 4; ++r) {
          int rl = wm*128 + i*16 + cr + r;  // 0..255
          sOut[rl*132 + ocl] = acc[i][2*j2][r] + acc[i][2*j2+1][r] + bv;
        }
    }
    __syncthreads();
    const int No = N >> 1;                  // 1024
#pragma unroll
    for (int sp = 0; sp < 16; ++sp) {
      int rl = sp*16 + (t >> 5);
      int c4 = (t & 31) * 4;
      f32x4 v = *(const f32x4*)&sOut[rl*132 + c4];
      size_t g = (size_t)(bm + rl) * No + (bn >> 1) + c4;
      if (J.mode == 2) {
        f16x4 o = {(f16)v[0], (f16)v[1], (f16)v[2], (f16)v[3]};
        *(f16x4*)&J.Ch[g] = o;
      } else {
        *(f32x4*)&J.Cf[g] = v;
      }
    }
  }
}

// ---------------- kv via MFMA: per (head, chunk of 512 rows) ---------------
#define SKT 72
__global__ __launch_bounds__(256) void k_kv_mfma(const f16* __restrict__ Kh,
                                                 const f16* __restrict__ Vh,
                                                 float* __restrict__ part) {
  __shared__ __align__(16) f16 sKt[64 * SKT];    // [d][l]
  __shared__ __align__(16) f16 sVt[128 * SKT];   // [c2][l]
  int head = blockIdx.x >> 3, chunk = blockIdx.x & 7;
  int b = head >> 4, h = head & 15;
  int t = threadIdx.x, lane = t & 63, wave = t >> 6;
  int lp = t & 31, g8 = (t >> 5) << 3;
  size_t rowbase = (size_t)b * L_ + (size_t)chunk * 512;
  const f16* Kb = Kh + rowbase * D_ + h * DH;
  const f16* Vb = Vh + rowbase * D_ + h * DH;

  const int fm = lane & 15, fk = (lane >> 4) << 3;
  const int wm2 = (wave & 1) * 2;
  const int wn4 = (wave >> 1) * 4;
  f32x4 acc[2][4] = {};

  for (int l0 = 0; l0 < 512; l0 += 64) {
    __syncthreads();
    {
      const f16* r0 = Kb + (size_t)(l0 + 2*lp) * D_ + g8;
      f16x8 a0 = *(const f16x8*)r0;
      f16x8 a1 = *(const f16x8*)(r0 + D_);
#pragma unroll
      for (int j = 0; j < 8; ++j) {
        union { f16 h2[2]; uint32_t u; } pk;
        pk.h2[0] = a0[j]; pk.h2[1] = a1[j];
        *(uint32_t*)&sKt[(g8 + j) * SKT + 2*lp] = pk.u;
      }
      const f16* v0p = Vb + (size_t)(l0 + 2*lp) * D_ + g8;
      f16x8 b0 = *(const f16x8*)v0p;
      f16x8 b1 = *(const f16x8*)(v0p + D_);
#pragma unroll
      for (int j = 0; j < 8; ++j) {
        float x0 = (float)b0[j], x1 = (float)b1[j];
        union { f16 h2[2]; uint32_t u; } pp, pm;
        pp.h2[0] = (f16)fmaxf(x0, 0.f); pp.h2[1] = (f16)fmaxf(x1, 0.f);
        pm.h2[0] = (f16)fminf(x0, 0.f); pm.h2[1] = (f16)fminf(x1, 0.f);
        *(uint32_t*)&sVt[(g8 + j) * SKT + 2*lp]        = pp.u;
        *(uint32_t*)&sVt[(64 + g8 + j) * SKT + 2*lp]   = pm.u;
      }
    }
    __syncthreads();
#pragma unroll
    for (int ks = 0; ks < 2; ++ks) {
      f16x8 af[2], bf[4];
#pragma unroll
      for (int i = 0; i < 2; ++i)
        af[i] = *(const f16x8*)&sKt[((wm2+i)*16 + fm) * SKT + ks*32 + fk];
#pragma unroll
      for (int j = 0; j < 4; ++j)
        bf[j] = *(const f16x8*)&sVt[((wn4+j)*16 + fm) * SKT + ks*32 + fk];
#pragma unroll
      for (int i = 0; i < 2; ++i)
#pragma unroll
        for (int j = 0; j < 4; ++j)
          acc[i][j] = MFMA(af[i], bf[j], acc[i][j]);
    }
  }
  const int cr = (lane >> 4) << 2, ccol = lane & 15;
  float* pb = part + (size_t)(head * 8 + chunk) * 8192;
#pragma unroll
  for (int i = 0; i < 2; ++i)
#pragma unroll
    for (int j = 0; j < 4; ++j) {
      int d = (wm2 + i) * 16 + cr;
      int c2 = (wn4 + j) * 16 + ccol;
#pragma unroll
      for (int r = 0; r < 4; ++r)
        pb[(d + r) * 128 + c2] = acc[i][j][r];
    }
}

// ---------------- fused reduce-over-chunks + transpose + f16 cvt -----------
__global__ __launch_bounds__(256) void k_kv_redcvt(const float* __restrict__ part,
                                                   f16* __restrict__ kvh) {
  int head = blockIdx.x, t = threadIdx.x;
  int c = t >> 1, half = t & 1;
  const float* src = part + (size_t)head * 8 * 8192 + half * 32 * 128 + c;
  f16* dst = kvh + (size_t)head * 8192 + c * 64 + half * 32;
  f16 buf[32];
#pragma unroll
  for (int kk = 0; kk < 32; ++kk) {
    float s = 0.f;
#pragma unroll
    for (int ch = 0; ch < 8; ++ch) s += src[(size_t)ch * 8192 + kk * 128];
    buf[kk] = (f16)s;
  }
#pragma unroll
  for (int q = 0; q < 4; ++q) ((f16x8*)dst)[q] = *(const f16x8*)&buf[q * 8];
}

// ---------------- heads via MFMA: o = l2n(Q@kv+) + l2n(Q@kv-) --------------
// Epilogue stages fp32 into LDS (union with sQ/sKV) -> coalesced 128B f16 rows.
#define SH 72
__global__ __launch_bounds__(256) void k_heads_mfma(const f16* __restrict__ Qh,
                                                    const f16* __restrict__ kvh,
                                                    f16* __restrict__ O) {
  __shared__ __align__(16) char hsmem[2 * 128 * SH * 2];  // 36864 B
  f16* sQ  = (f16*)hsmem;
  f16* sKV = (f16*)(hsmem + 128 * SH * 2);
  int bi = blockIdx.x;
  int head = bi >> 5, mt = bi & 31;
  int b = head >> 4, h = head & 15;
  int t = threadIdx.x, lane = t & 63, wave = t >> 6;
  size_t qbase = ((size_t)(b * L_ + mt * 128)) * D_ + h * DH;
  const f16* kvp = kvh + (size_t)head * 8192;
#pragma unroll
  for (int p = 0; p < 4; ++p) {
    int c = p * 256 + t;
    int row = c >> 3, off = (c & 7) * 8;
    f16x8 q = *(const f16x8*)(Qh + qbase + (size_t)row * D_ + off);
    *(f16x8*)&sQ[row * SH + off] = q;
    f16x8 kv8 = *(const f16x8*)(kvp + row * 64 + off);
    *(f16x8*)&sKV[row * SH + off] = kv8;
  }
  __syncthreads();

  const int fm = lane & 15, fk = (lane >> 4) << 3;
  const int wm = wave * 32;
  f32x4 acc[2][8] = {};
#pragma unroll
  for (int ks = 0; ks < 2; ++ks) {
    f16x8 a0 = *(const f16x8*)&sQ[(wm + fm) * SH + ks * 32 + fk];
    f16x8 a1 = *(const f16x8*)&sQ[(wm + 16 + fm) * SH + ks * 32 + fk];
#pragma unroll
    for (int j = 0; j < 8; ++j) {
      f16x8 bj = *(const f16x8*)&sKV[(j * 16 + fm) * SH + ks * 32 + fk];
      acc[0][j] = MFMA(a0, bj, acc[0][j]);
      acc[1][j] = MFMA(a1, bj, acc[1][j]);
    }
  }
  __syncthreads();   // all LDS frag reads done before overwriting as sOf
  float* sOf = (float*)hsmem;   // [128][68]: +4 rows -> +16 banks; pitch 272B
  const int cr = (lane >> 4) << 2, ccol = lane & 15;
#pragma unroll
  for (int i = 0; i < 2; ++i)
#pragma unroll
    for (int r = 0; r < 4; ++r) {
      int row = wm + i * 16 + cr + r;
      float sp = 0.f, sm = 0.f;
#pragma unroll
      for (int j = 0; j < 4; ++j) {
        sp += acc[i][j][r] * acc[i][j][r];
        sm += acc[i][j + 4][r] * acc[i][j + 4][r];
      }
      sp += __shfl_xor(sp, 1, 64); sm += __shfl_xor(sm, 1, 64);
      sp += __shfl_xor(sp, 2, 64); sm += __shfl_xor(sm, 2, 64);
      sp += __shfl_xor(sp, 4, 64); sm += __shfl_xor(sm, 4, 64);
      sp += __shfl_xor(sp, 8, 64); sm += __shfl_xor(sm, 8, 64);
      float rp = 1.0f / fmaxf(sqrtf(sp), 1e-12f);
      float rm = 1.0f / fmaxf(sqrtf(sm), 1e-12f);
#pragma unroll
      for (int j = 0; j < 4; ++j)
        sOf[row * 68 + j * 16 + ccol] = acc[i][j][r] * rp + acc[i][j + 4][r] * rm;
    }
  __syncthreads();
#pragma unroll
  for (int sp = 0; sp < 8; ++sp) {
    int rl = sp * 16 + (t >> 4);
    int c4 = (t & 15) * 4;
    f32x4 v = *(const f32x4*)&sOf[rl * 68 + c4];
    f16x4 o = {(f16)v[0], (f16)v[1], (f16)v[2], (f16)v[3]};
    *(f16x4*)&O[qbase + (size_t)rl * D_ + c4] = o;
  }
}

// ---------------- launch ----------------
extern "C" void kernel_launch(void* const* d_in, const int* in_sizes, int n_in,
                              void* d_out, int out_size, void* d_ws, size_t ws_size,
                              hipStream_t stream) {
  const float* queries = (const float*)d_in[0];
  const float* values  = (const float*)d_in[1];
  const float* keys    = (const float*)d_in[2];
  const float* mask    = (const float*)d_in[3];
  const float* Wq = (const float*)d_in[4];  const float* bq = (const float*)d_in[5];
  const float* Wk = (const float*)d_in[6];  const float* bk = (const float*)d_in[7];
  const float* Wv = (const float*)d_in[8];  const float* bv = (const float*)d_in[9];
  const float* Wo = (const float*)d_in[10]; const float* bo = (const float*)d_in[11];
  float* out = (float*)d_out;

  const size_t MB = 1024ull * 1024ull;
  const size_t NEED = 160 * MB;
  if (ws_size < NEED) return;

  char* ws = (char*)d_ws;
  const size_t DD = (size_t)D_ * D_;
  f16*   Wqh  = (f16*)(ws);                 // 2MB
  f16*   Wkh  = (f16*)(ws + 2 * MB);        // 2MB
  f16*   Wcv  = (f16*)(ws + 4 * MB);        // 4MB interleaved [hi;lo] V weight
  f16*   Wco  = (f16*)(ws + 8 * MB);        // 4MB interleaved [hi;lo] O weight
  f16*   Ah   = (f16*)(ws + 12 * MB);       // 32MB (q16 / v16 / heads out)
  f16*   Qh   = (f16*)(ws + 44 * MB);       // 32MB
  f16*   kvh  = (f16*)(ws + 78 * MB);       // 1MB (+1MB pad)
  float* part = (float*)(ws + 80 * MB);     // 16MB
  f16*   kp   = (f16*)(ws + 96 * MB);       // 32MB
  f16*   vp   = (f16*)(ws + 128 * MB);      // 32MB (k16 before V-GEMM) -> 160MB

  const int DD8 = (int)(DD / 8);            // 131072
  const int DD4 = (int)(DD / 4);            // 262144
  const int n8  = M_ * D_ / 8;              // 2097152

  f16* q16 = Ah;
  f16* k16 = vp;    // vp region free until V-GEMM writes it (after QK-GEMM)
  f16* v16 = Ah;    // after QK-GEMM consumed q16

  // weight prep (2 launches)
  k_cvt2 <<<2 * DD8 / 256, 256, 0, stream>>>(Wq, Wqh, Wk, Wkh, DD8);
  k_split2<<<2 * DD4 / 256, 256, 0, stream>>>(Wv, Wcv, Wo, Wco, DD4);

  // cast queries+keys, then combined Q|K GEMM (512 blocks, 2 jobs)
  k_cvt2<<<2 * n8 / 256, 256, 0, stream>>>(queries, q16, keys, k16, n8);
  {
    GemmJob jq = { q16, Wqh, bq, nullptr, nullptr, Qh, 1, 1024 };
    GemmJob jk = { k16, Wkh, bk, mask,    nullptr, kp, 1, 1024 };
    k_gemm8<<<512, 512, 0, stream>>>(jq, jk, 256, M_, 1024);
  }

  // cast values, V GEMM (weight-split fold, f16 out)
  k_cvt_f16<<<n8 / 256, 256, 0, stream>>>(values, v16, n8);
  {
    GemmJob jv = { v16, Wcv, bv, nullptr, nullptr, vp, 2, 2048 };
    k_gemm8<<<512, 512, 0, stream>>>(jv, jv, 512, M_, 1024);
  }

  k_kv_mfma<<<64 * 8, 256, 0, stream>>>(kp, vp, part);
  k_kv_redcvt<<<64, 256, 0, stream>>>(part, kvh);
  k_heads_mfma<<<64 * 32, 256, 0, stream>>>(Qh, kvh, Ah);

  {
    GemmJob jo = { Ah, Wco, bo, nullptr, out, nullptr, 3, 2048 };
    k_gemm8<<<512, 512, 0, stream>>>(jo, jo, 512, M_, 1024);
  }
}